// Round 3
// baseline (484.218 us; speedup 1.0000x reference)
//
#include <hip/hip_runtime.h>
#include <float.h>

// Top-left corner pooling: out = 2 * rev_cummax_W(rev_cummax_H(x))
// x: (16, 256, 128, 128) fp32 -> 4096 planes of 128x128.
//
// Round-3: two-pass strip decomposition. Rounds 1-2 (one wave per plane,
// lockstep h=127..0) were stuck at 430 us (~1.25 TB/s) regardless of the
// scan implementation -> memory-pattern-bound (lockstep same-offset access
// across 64KB-strided planes + thin MLP at 8 waves/CU).
//
// Pass A: wave64 per (plane, strip of 16 rows): strip column-max -> ws.
//         16 batched 512B loads per wave (8KB MLP), 32768 waves.
// Pass B: wave64 per (plane, strip): tail = suffix-max of deeper strip
//         summaries from ws; then rows 15..0: cm = max(cm,row), 64-lane
//         DPP suffix scan over W, store 2*r. Concurrent waves span 8
//         different h-bands -> no device-wide offset lockstep.
// Traffic: 256R + 16W + 272R + 256W = 800 MB -> 127 us floor @ 6.3 TB/s.

#define DPP_ROW_SHR1 0x111
#define DPP_ROW_SHR2 0x112
#define DPP_ROW_SHR4 0x114
#define DPP_ROW_SHR8 0x118
#define DPP_ROW_BCAST15 0x142
#define DPP_ROW_BCAST31 0x143
#define DPP_WAVE_SHR1 0x138

template <int CTRL, int ROW_MASK>
__device__ __forceinline__ float dpp_mov_f(float src) {
  // old = -FLT_MAX: lanes with no valid source get the max-identity.
  const int old = (int)0xFF7FFFFFu;  // bit pattern of -FLT_MAX
  int r = __builtin_amdgcn_update_dpp(old, __builtin_bit_cast(int, src),
                                      CTRL, ROW_MASK, 0xF, false);
  return __builtin_bit_cast(float, r);
}

__device__ __forceinline__ float2 f2max(float2 a, float2 b) {
  return make_float2(fmaxf(a.x, b.x), fmaxf(a.y, b.y));
}

// ---------------- Pass A: per-strip column max ----------------
__global__ __launch_bounds__(256) void strip_max_kernel(
    const float* __restrict__ x, float* __restrict__ ws, int planes) {
  const int wid = (blockIdx.x * blockDim.x + threadIdx.x) >> 6;
  const int lane = threadIdx.x & 63;
  if (wid >= planes * 8) return;
  const int plane = wid >> 3;
  const int strip = wid & 7;

  const float2* __restrict__ p =
      (const float2*)(x + (size_t)plane * 16384 + (size_t)strip * 16 * 128) +
      lane;

  float2 v[16];
#pragma unroll
  for (int r = 0; r < 16; ++r) v[r] = p[r * 64];  // 16 loads batched -> 8KB MLP

  float2 m = v[0];
#pragma unroll
  for (int r = 1; r < 16; ++r) m = f2max(m, v[r]);

  ((float2*)ws)[(size_t)wid * 64 + lane] = m;
}

// ---------------- Pass B: finish H-scan + W-scan + store ----------------
__global__ __launch_bounds__(256) void corner_pool_strip_kernel(
    const float* __restrict__ x, const float* __restrict__ ws,
    float* __restrict__ out, int planes) {
  const int wid = (blockIdx.x * blockDim.x + threadIdx.x) >> 6;
  const int lane = threadIdx.x & 63;
  if (wid >= planes * 8) return;
  const int plane = wid >> 3;
  const int strip = wid & 7;

  const float NINF = -FLT_MAX;
  // Reversed lane->column mapping so the W suffix scan is a forward
  // (DPP-friendly) lane-prefix scan: lane j holds float2 index 63-j,
  // i.e. columns 126-2j, 127-2j.
  const int rv = 63 - lane;

  // Tail: columnwise max over all strips strictly below this one.
  const float2* __restrict__ sm =
      (const float2*)ws + (size_t)plane * 8 * 64 + rv;
  float2 cm = make_float2(NINF, NINF);
  for (int s2 = strip + 1; s2 < 8; ++s2) cm = f2max(cm, sm[s2 * 64]);

  const float2* __restrict__ xr =
      (const float2*)(x + (size_t)plane * 16384 + (size_t)strip * 2048) + rv;
  float2* __restrict__ yr =
      (float2*)(out + (size_t)plane * 16384 + (size_t)strip * 2048) + rv;

  float2 v[16];
#pragma unroll
  for (int r = 0; r < 16; ++r) v[r] = xr[r * 64];  // whole strip in flight

#pragma unroll
  for (int r = 15; r >= 0; --r) {
    // H suffix max (carried): cm = max over rows >= this one (incl. tail)
    cm = f2max(cm, v[r]);

    // W suffix scan. Intra-lane: col c -> max(cm.x, cm.y); col c+1 -> cm.y.
    float M = fmaxf(cm.x, cm.y);

    // Inclusive 64-lane prefix max, pure VALU DPP (gfx9 scan idiom).
    float g = M;
    g = fmaxf(g, dpp_mov_f<DPP_ROW_SHR1, 0xF>(g));
    g = fmaxf(g, dpp_mov_f<DPP_ROW_SHR2, 0xF>(g));
    g = fmaxf(g, dpp_mov_f<DPP_ROW_SHR4, 0xF>(g));
    g = fmaxf(g, dpp_mov_f<DPP_ROW_SHR8, 0xF>(g));
    g = fmaxf(g, dpp_mov_f<DPP_ROW_BCAST15, 0xA>(g));  // rows 1,3 <- lane15/47
    g = fmaxf(g, dpp_mov_f<DPP_ROW_BCAST31, 0xC>(g));  // rows 2,3 <- lane31

    // Exclusive prefix (lanes strictly before = columns strictly after).
    float e = dpp_mov_f<DPP_WAVE_SHR1, 0xF>(g);
    e = (lane == 0) ? NINF : e;

    float2 r2;
    r2.x = g;                 // max(intra-lane suffix at col c, e)
    r2.y = fmaxf(cm.y, e);    // col c+1
    r2.x += r2.x;             // out = y + y
    r2.y += r2.y;
    yr[r * 64] = r2;
  }
}

extern "C" void kernel_launch(void* const* d_in, const int* in_sizes, int n_in,
                              void* d_out, int out_size, void* d_ws,
                              size_t ws_size, hipStream_t stream) {
  const float* x = (const float*)d_in[0];
  float* out = (float*)d_out;
  float* ws = (float*)d_ws;

  const int plane_elems = 128 * 128;
  const int planes = in_sizes[0] / plane_elems;  // 4096

  const int block = 256;  // 4 waves per block
  const int total_waves = planes * 8;
  const int grid = (total_waves * 64 + block - 1) / block;  // 8192 blocks

  strip_max_kernel<<<grid, block, 0, stream>>>(x, ws, planes);
  corner_pool_strip_kernel<<<grid, block, 0, stream>>>(x, ws, out, planes);
}

// Round 4
// 449.819 us; speedup vs baseline: 1.0765x; 1.0765x over previous
//
#include <hip/hip_runtime.h>
#include <float.h>

// Top-left corner pooling: out = 2 * rev_cummax_W(rev_cummax_H(x))
// x: (16, 256, 128, 128) fp32 -> 4096 planes of 128x128.
//
// Round-4: single-pass block-cooperative version. Key findings so far:
//  - bench dur_us carries ~285 us of fixed harness overhead (1 GiB ws poison
//    + out poison + input restore fills at ~165 us dominate rocprof top-5);
//    controllable kernel time in R1/R2 was ~145 us (3.7 TB/s).
//  - R3 pass A (batched strip loads, tiny store) ran near 5.4 TB/s -> batched
//    register-resident strips load well; a second full pass is a pure loss.
//
// Structure: one block (4 waves) per plane. Wave w owns rows [32w, 32w+32),
// held ENTIRELY in registers (32 x float2 = 64 VGPRs). Phases:
//  1. batch-load 32 rows (16 KB in flight per wave, pass-A-like),
//     reduce to strip column-max
//  2. exchange strip column-maxima via 2 KB LDS, one __syncthreads
//  3. tail = max of deeper strips' maxima; replay rows 31..0 from registers:
//     cm = f2max(cm, v[r]); 64-lane DPP prefix-max (lanes reversed vs
//     columns so the W suffix scan is a forward DPP scan); nontemporal
//     float2 store of 2*result.
// Traffic: exactly 1R + 1W per element = 512 MB -> 81 us floor @ 6.3 TB/s.

#define DPP_ROW_SHR1 0x111
#define DPP_ROW_SHR2 0x112
#define DPP_ROW_SHR4 0x114
#define DPP_ROW_SHR8 0x118
#define DPP_ROW_BCAST15 0x142
#define DPP_ROW_BCAST31 0x143
#define DPP_WAVE_SHR1 0x138

template <int CTRL, int ROW_MASK>
__device__ __forceinline__ float dpp_mov_f(float src) {
  // old = -FLT_MAX: lanes with no valid source get the max-identity.
  const int old = (int)0xFF7FFFFFu;  // bit pattern of -FLT_MAX
  int r = __builtin_amdgcn_update_dpp(old, __builtin_bit_cast(int, src),
                                      CTRL, ROW_MASK, 0xF, false);
  return __builtin_bit_cast(float, r);
}

__device__ __forceinline__ float2 f2max(float2 a, float2 b) {
  return make_float2(fmaxf(a.x, b.x), fmaxf(a.y, b.y));
}

typedef float f2v __attribute__((ext_vector_type(2)));

__global__ __launch_bounds__(256) void corner_pool_block_kernel(
    const float* __restrict__ x, float* __restrict__ out) {
  constexpr int H = 128;
  constexpr int W = 128;
  constexpr int WAVES = 4;
  constexpr int ROWS = H / WAVES;  // 32 rows per wave, register-resident

  __shared__ float2 smax[WAVES][64];

  const int wv = threadIdx.x >> 6;   // wave id == strip index (0 = top)
  const int lane = threadIdx.x & 63;
  const int plane = blockIdx.x;

  const float NINF = -FLT_MAX;
  // Reversed lane->column map: lane j holds float2 index 63-j (columns
  // 126-2j, 127-2j), so the column SUFFIX max is a forward lane PREFIX max
  // (DPP row_shr runs forward only).
  const int rv = 63 - lane;

  const float2* __restrict__ xr =
      (const float2*)(x + (size_t)plane * H * W) + (size_t)wv * ROWS * 64 + rv;
  float2* __restrict__ yr =
      (float2*)(out + (size_t)plane * H * W) + (size_t)wv * ROWS * 64 + rv;

  // Phase 1: whole strip into registers (16 KB of loads in flight).
  float2 v[ROWS];
#pragma unroll
  for (int r = 0; r < ROWS; ++r) v[r] = xr[r * 64];

  float2 m = v[0];
#pragma unroll
  for (int r = 1; r < ROWS; ++r) m = f2max(m, v[r]);

  // Phase 2: exchange per-strip column maxima (indexed by lane: all waves
  // use the same lane->column map, so same-lane entries align).
  smax[wv][lane] = m;
  __syncthreads();

  // Tail: column max over strips strictly below this one.
  float2 cm = make_float2(NINF, NINF);
  for (int w2 = wv + 1; w2 < WAVES; ++w2) cm = f2max(cm, smax[w2][lane]);

  // Phase 3: bottom-up replay from registers; W-scan; streaming store.
#pragma unroll
  for (int r = ROWS - 1; r >= 0; --r) {
    cm = f2max(cm, v[r]);  // H suffix max at this row

    // Intra-lane: col c -> max(cm.x, cm.y); col c+1 -> cm.y.
    float M = fmaxf(cm.x, cm.y);

    // Inclusive 64-lane prefix max (pure VALU DPP, gfx9 scan idiom).
    float g = M;
    g = fmaxf(g, dpp_mov_f<DPP_ROW_SHR1, 0xF>(g));
    g = fmaxf(g, dpp_mov_f<DPP_ROW_SHR2, 0xF>(g));
    g = fmaxf(g, dpp_mov_f<DPP_ROW_SHR4, 0xF>(g));
    g = fmaxf(g, dpp_mov_f<DPP_ROW_SHR8, 0xF>(g));
    g = fmaxf(g, dpp_mov_f<DPP_ROW_BCAST15, 0xA>(g));  // rows 1,3 <- 15/47
    g = fmaxf(g, dpp_mov_f<DPP_ROW_BCAST31, 0xC>(g));  // rows 2,3 <- 31

    // Exclusive prefix (lanes before = columns after).
    float e = dpp_mov_f<DPP_WAVE_SHR1, 0xF>(g);
    e = (lane == 0) ? NINF : e;

    f2v r2;
    r2.x = g + g;                      // out = y + y at col c
    float oy = fmaxf(cm.y, e);
    r2.y = oy + oy;                    // col c+1
    __builtin_nontemporal_store(r2, (f2v*)&yr[r * 64]);
  }
}

extern "C" void kernel_launch(void* const* d_in, const int* in_sizes, int n_in,
                              void* d_out, int out_size, void* d_ws,
                              size_t ws_size, hipStream_t stream) {
  const float* x = (const float*)d_in[0];
  float* out = (float*)d_out;

  const int plane_elems = 128 * 128;
  const int planes = in_sizes[0] / plane_elems;  // 4096

  corner_pool_block_kernel<<<planes, 256, 0, stream>>>(x, out);
}

// Round 5
// 436.890 us; speedup vs baseline: 1.1083x; 1.0296x over previous
//
#include <hip/hip_runtime.h>
#include <float.h>

// Top-left corner pooling: out = 2 * rev_cummax_W(rev_cummax_H(x))
// x: (16, 256, 128, 128) fp32 -> 4096 planes of 128x128.
//
// Round-5: burst-phase structure. Evidence from R1-R4: every variant that
// issues memory ops one-at-a-time from inside a dependent scan chain lands
// at 145-165 us (~3.4 TB/s); batched-independent-load pass (R3A) ran 5.4
// TB/s and the write-only fill 6.4 TB/s. So: make every memory phase a
// burst of independent ops, keep the scan chain memory-free.
//
// One block (512 threads = 8 waves) per plane; wave w owns rows
// [16w, 16w+16) as float2/lane, register-resident.
//   P1: 16 independent loads -> v[16] (the proven R3A pattern), strip max
//   P2: 4 KB LDS exchange of per-strip column maxima, one barrier
//   P3a: rows 15..0: cm=max(cm,v[r]); 64-lane DPP W-suffix-scan; result
//        back into v[r]. NO memory ops in this chain.
//   P3b: 16 back-to-back independent stores (fill-like burst).
// Lanes are reversed vs columns (lane j <-> float2 index 63-j) so the
// column suffix scan is a forward DPP prefix scan.
// Traffic: exactly 1R + 1W per element.

#define DPP_ROW_SHR1 0x111
#define DPP_ROW_SHR2 0x112
#define DPP_ROW_SHR4 0x114
#define DPP_ROW_SHR8 0x118
#define DPP_ROW_BCAST15 0x142
#define DPP_ROW_BCAST31 0x143
#define DPP_WAVE_SHR1 0x138

template <int CTRL, int ROW_MASK>
__device__ __forceinline__ float dpp_mov_f(float src) {
  // old = -FLT_MAX: lanes with no valid source get the max-identity.
  const int old = (int)0xFF7FFFFFu;  // bit pattern of -FLT_MAX
  int r = __builtin_amdgcn_update_dpp(old, __builtin_bit_cast(int, src),
                                      CTRL, ROW_MASK, 0xF, false);
  return __builtin_bit_cast(float, r);
}

__device__ __forceinline__ float2 f2max(float2 a, float2 b) {
  return make_float2(fmaxf(a.x, b.x), fmaxf(a.y, b.y));
}

__global__ __launch_bounds__(512) void corner_pool_burst_kernel(
    const float* __restrict__ x, float* __restrict__ out) {
  constexpr int H = 128;
  constexpr int W = 128;
  constexpr int WAVES = 8;
  constexpr int ROWS = H / WAVES;  // 16 rows per wave

  __shared__ float2 smax[WAVES][64];

  const int wv = threadIdx.x >> 6;  // strip index, 0 = top
  const int lane = threadIdx.x & 63;
  const int plane = blockIdx.x;

  const float NINF = -FLT_MAX;
  const int rv = 63 - lane;  // reversed lane->column map

  const float* base = x + (size_t)plane * H * W;
  const float2* __restrict__ xr =
      (const float2*)base + (size_t)wv * ROWS * 64 + rv;
  float2* __restrict__ yr =
      (float2*)(out + (size_t)plane * H * W) + (size_t)wv * ROWS * 64 + rv;

  // ---- Phase 1: burst of 16 independent loads ----
  float2 v[ROWS];
#pragma unroll
  for (int r = 0; r < ROWS; ++r) v[r] = xr[r * 64];

  float2 m = v[0];
#pragma unroll
  for (int r = 1; r < ROWS; ++r) m = f2max(m, v[r]);

  // ---- Phase 2: strip-max exchange ----
  smax[wv][lane] = m;
  __syncthreads();

  float2 cm = make_float2(NINF, NINF);
#pragma unroll
  for (int w2 = 0; w2 < WAVES; ++w2)
    if (w2 > wv) cm = f2max(cm, smax[w2][lane]);

  // ---- Phase 3a: memory-free scan chain, results into v[] ----
#pragma unroll
  for (int r = ROWS - 1; r >= 0; --r) {
    cm = f2max(cm, v[r]);  // H suffix max at this row

    float M = fmaxf(cm.x, cm.y);  // intra-lane suffix at col c

    // Inclusive 64-lane prefix max (pure VALU DPP).
    float g = M;
    g = fmaxf(g, dpp_mov_f<DPP_ROW_SHR1, 0xF>(g));
    g = fmaxf(g, dpp_mov_f<DPP_ROW_SHR2, 0xF>(g));
    g = fmaxf(g, dpp_mov_f<DPP_ROW_SHR4, 0xF>(g));
    g = fmaxf(g, dpp_mov_f<DPP_ROW_SHR8, 0xF>(g));
    g = fmaxf(g, dpp_mov_f<DPP_ROW_BCAST15, 0xA>(g));  // rows 1,3 <- 15/47
    g = fmaxf(g, dpp_mov_f<DPP_ROW_BCAST31, 0xC>(g));  // rows 2,3 <- 31

    float e = dpp_mov_f<DPP_WAVE_SHR1, 0xF>(g);
    e = (lane == 0) ? NINF : e;

    float2 r2;
    r2.x = g + g;  // out = y + y
    float oy = fmaxf(cm.y, e);
    r2.y = oy + oy;
    v[r] = r2;
  }

  // ---- Phase 3b: burst of 16 independent stores ----
#pragma unroll
  for (int r = 0; r < ROWS; ++r) yr[r * 64] = v[r];
}

extern "C" void kernel_launch(void* const* d_in, const int* in_sizes, int n_in,
                              void* d_out, int out_size, void* d_ws,
                              size_t ws_size, hipStream_t stream) {
  const float* x = (const float*)d_in[0];
  float* out = (float*)d_out;

  const int plane_elems = 128 * 128;
  const int planes = in_sizes[0] / plane_elems;  // 4096

  corner_pool_burst_kernel<<<planes, 512, 0, stream>>>(x, out);
}